// Round 5
// baseline (352.152 us; speedup 1.0000x reference)
//
#include <hip/hip_runtime.h>
#include <hip/hip_bf16.h>

#define S_LEN 8192
#define DM    1024
#define DK    128
#define NWA   4      // waves per flash_partial block
#define PSTR  136    // P LDS row stride in bf16 (2-way max bank aliasing)
#define PARTSZ 2080  // floats per partial slot: m[16] l[16] O[16*128]

typedef __attribute__((ext_vector_type(8))) short bf16x8;
typedef __attribute__((ext_vector_type(8))) _Float16 f16x8;
typedef __attribute__((ext_vector_type(4))) float f32x4;

__device__ __forceinline__ f32x4 mfma16(bf16x8 a, bf16x8 b, f32x4 c) {
    return __builtin_amdgcn_mfma_f32_16x16x32_bf16(a, b, c, 0, 0, 0);
}

// fp32 -> bf16 (RNE)
__device__ __forceinline__ ushort f2bf(float f) {
    unsigned u = __builtin_bit_cast(unsigned, f);
    u += 0x7FFFu + ((u >> 16) & 1u);
    return (ushort)(u >> 16);
}

// ---------------------------------------------------------------------------
// fp32 -> fp16 conversion of X (8192x1024) and Wq|Wk|Wv (each 128x1024).
// ---------------------------------------------------------------------------
__global__ __launch_bounds__(256, 1)
void convert_kernel(const float* __restrict__ X,
                    const float* __restrict__ Wq,
                    const float* __restrict__ Wk,
                    const float* __restrict__ Wv,
                    _Float16* __restrict__ Xh,
                    _Float16* __restrict__ Wh) {
    const int NX4 = S_LEN * DM / 4;
    const int NW4 = DK * DM / 4;
    const int total4 = NX4 + 3 * NW4;
    for (int i = blockIdx.x * 256 + threadIdx.x; i < total4; i += gridDim.x * 256) {
        const float4* src;
        _Float16* dst;
        int off;
        if (i < NX4) {
            src = (const float4*)X; dst = Xh; off = i;
        } else {
            const int w = i - NX4;
            const int which = w / NW4;
            off = w - which * NW4;
            src = (const float4*)(which == 0 ? Wq : (which == 1 ? Wk : Wv));
            dst = Wh + which * (DK * DM);
        }
        const float4 v = src[off];
        union { _Float16 h[4]; uint2 u; } p;
        p.h[0] = (_Float16)v.x; p.h[1] = (_Float16)v.y;
        p.h[2] = (_Float16)v.z; p.h[3] = (_Float16)v.w;
        *(uint2*)(dst + (size_t)off * 4) = p.u;
    }
}

// ---------------------------------------------------------------------------
// Projection GEMM (fp16 MFMA): C[8192x384] = Xh[8192x1024] @ Wh^T.
// ---------------------------------------------------------------------------
__global__ __launch_bounds__(256)
void proj_gemm_kernel(const _Float16* __restrict__ Xh,
                      const _Float16* __restrict__ Wh,
                      ushort* __restrict__ Qb,
                      ushort* __restrict__ Kb,
                      ushort* __restrict__ Vtb) {
    __shared__ _Float16 Ash[128 * 32];
    __shared__ _Float16 Bsh[128 * 32];

    const int tid  = threadIdx.x;
    const int lane = tid & 63;
    const int quad = lane >> 4;
    const int l15  = lane & 15;
    const int wv   = tid >> 6;
    const int wm   = wv & 1;
    const int wn   = wv >> 1;
    const int m0   = blockIdx.x * 128;
    const int nb   = blockIdx.y;
    const _Float16* Wbase = Wh + nb * (DK * DM);

    f32x4 acc[4][4];
#pragma unroll
    for (int mi = 0; mi < 4; ++mi)
#pragma unroll
        for (int ni = 0; ni < 4; ++ni) acc[mi][ni] = (f32x4){0.f, 0.f, 0.f, 0.f};

    for (int kk = 0; kk < DM; kk += 32) {
        __syncthreads();
#pragma unroll
        for (int s = tid; s < 512; s += 256) {
            const int row = s >> 2, sg = s & 3;
            __builtin_amdgcn_global_load_lds(
                (const __attribute__((address_space(1))) void*)(Xh + (size_t)(m0 + row) * DM + kk + sg * 8),
                (__attribute__((address_space(3))) void*)(Ash + s * 8), 16, 0, 0);
            __builtin_amdgcn_global_load_lds(
                (const __attribute__((address_space(1))) void*)(Wbase + (size_t)row * DM + kk + sg * 8),
                (__attribute__((address_space(3))) void*)(Bsh + s * 8), 16, 0, 0);
        }
        __syncthreads();

        f16x8 af[4], bf[4];
#pragma unroll
        for (int t = 0; t < 4; ++t) {
            af[t] = *(const f16x8*)(Ash + (wm * 64 + t * 16 + l15) * 32 + quad * 8);
            bf[t] = *(const f16x8*)(Bsh + (wn * 64 + t * 16 + l15) * 32 + quad * 8);
        }
#pragma unroll
        for (int mi = 0; mi < 4; ++mi)
#pragma unroll
            for (int ni = 0; ni < 4; ++ni)
                acc[mi][ni] = __builtin_amdgcn_mfma_f32_16x16x32_f16(af[mi], bf[ni], acc[mi][ni], 0, 0, 0);
    }

    if (nb == 2) {
#pragma unroll
        for (int mi = 0; mi < 4; ++mi)
#pragma unroll
            for (int ni = 0; ni < 4; ++ni) {
                const int n = wn * 64 + ni * 16 + l15;
                const int m = m0 + wm * 64 + mi * 16 + quad * 4;
                union { ushort h[4]; uint2 u; } p;
#pragma unroll
                for (int r = 0; r < 4; ++r) p.h[r] = f2bf(acc[mi][ni][r]);
                *(uint2*)(Vtb + (size_t)n * S_LEN + m) = p.u;
            }
    } else {
        ushort* Ob = (nb == 0) ? Qb : Kb;
        const float sc = (nb == 0) ? 0.088388347648318447f * 1.4426950408889634f : 1.0f;
#pragma unroll
        for (int mi = 0; mi < 4; ++mi)
#pragma unroll
            for (int ni = 0; ni < 4; ++ni) {
                const int n = wn * 64 + ni * 16 + l15;
#pragma unroll
                for (int r = 0; r < 4; ++r) {
                    const int m = m0 + wm * 64 + mi * 16 + quad * 4 + r;
                    Ob[(size_t)m * DK + n] = f2bf(acc[mi][ni][r] * sc);
                }
            }
    }
}

// ---------------------------------------------------------------------------
// Flash attention partials: split-K across blocks for occupancy.
// 1280 blocks x 256 thr (4 waves). Work item = (q-tile qt, chunk of k-tiles):
//   qt in [0,128): 1 chunk; [128,256): 2; [256,384): 3; [384,512): 4.
// Chunk = even split of nkt 128-key tiles; intra-block 4-way split-K,
// merged in LDS; partial (m,l,O) written fp32 to workspace.
// ---------------------------------------------------------------------------
__global__ __launch_bounds__(256, 5)
void flash_partial_kernel(const ushort* __restrict__ Qg,
                          const ushort* __restrict__ Kg,
                          const ushort* __restrict__ Vtg,
                          float* __restrict__ Part) {
    __shared__ __align__(16) ushort Plds[NWA * 16 * PSTR];
    __shared__ __align__(16) float mergeO[16 * 132];
    __shared__ float mergeL[16];
    __shared__ float mlbuf[NWA][16][2];

    const int b = blockIdx.x;
    int qt, chunk, P;
    if (b < 128)      { qt = b;                  chunk = 0;            P = 1; }
    else if (b < 384) { qt = 128 + ((b - 128) >> 1); chunk = (b - 128) & 1; P = 2; }
    else if (b < 768) { qt = 256 + (b - 384) / 3;    chunk = (b - 384) % 3; P = 3; }
    else              { qt = 384 + ((b - 768) >> 2); chunk = (b - 768) & 3; P = 4; }

    const int q0    = qt * 16;
    const int nkt   = (q0 + 16 + 127) >> 7;
    const int kt_lo = (chunk * nkt) / P;
    const int kt_hi = ((chunk + 1) * nkt) / P;

    const int tid  = threadIdx.x;
    const int wv   = tid >> 6;
    const int lane = tid & 63;
    const int quad = lane >> 4;
    const int l15  = lane & 15;
    ushort* Pl = Plds + wv * 16 * PSTR;

    for (int i = tid; i < 16 * 132; i += 256) mergeO[i] = 0.f;
    if (tid < 16) mergeL[tid] = 0.f;

    // Q fragments (A layout), resident
    bf16x8 qf[4];
    {
        const ushort* qrow = Qg + (size_t)(q0 + l15) * DK + quad * 8;
#pragma unroll
        for (int kc = 0; kc < 4; ++kc) qf[kc] = *(const bf16x8*)(qrow + kc * 32);
    }

    float m_[4], l_[4];
#pragma unroll
    for (int r = 0; r < 4; ++r) { m_[r] = -__builtin_inff(); l_[r] = 0.f; }
    f32x4 acc[8];
#pragma unroll
    for (int d = 0; d < 8; ++d) acc[d] = (f32x4){0.f, 0.f, 0.f, 0.f};

    for (int kt = kt_lo + wv; kt < kt_hi; kt += NWA) {
        const int k0 = kt << 7;

        // S = Q K^T (16 x 128), C layout
        f32x4 Sr[8];
#pragma unroll
        for (int nb = 0; nb < 8; ++nb) {
            Sr[nb] = (f32x4){0.f, 0.f, 0.f, 0.f};
            const ushort* krow = Kg + (size_t)(k0 + nb * 16 + l15) * DK + quad * 8;
#pragma unroll
            for (int kc = 0; kc < 4; ++kc)
                Sr[nb] = mfma16(qf[kc], *(const bf16x8*)(krow + kc * 32), Sr[nb]);
        }

        // causal mask (diagonal tile only)
        if (k0 + 127 > q0) {
#pragma unroll
            for (int nb = 0; nb < 8; ++nb) {
                const int kg = k0 + nb * 16 + l15;
#pragma unroll
                for (int r = 0; r < 4; ++r)
                    if (kg > q0 + quad * 4 + r) Sr[nb][r] = -__builtin_inff();
            }
        }

        // online softmax (exp2 domain)
        float al[4], rs[4];
#pragma unroll
        for (int r = 0; r < 4; ++r) {
            float v = m_[r];
#pragma unroll
            for (int nb = 0; nb < 8; ++nb) v = fmaxf(v, Sr[nb][r]);
            v = fmaxf(v, __shfl_xor(v, 1));
            v = fmaxf(v, __shfl_xor(v, 2));
            v = fmaxf(v, __shfl_xor(v, 4));
            v = fmaxf(v, __shfl_xor(v, 8));
            al[r] = exp2f(m_[r] - v);
            m_[r] = v;
            rs[r] = 0.f;
        }
#pragma unroll
        for (int nb = 0; nb < 8; ++nb) {
#pragma unroll
            for (int r = 0; r < 4; ++r) {
                const float p = exp2f(Sr[nb][r] - m_[r]);
                rs[r] += p;
                Pl[(quad * 4 + r) * PSTR + nb * 16 + l15] = f2bf(p);
            }
        }
#pragma unroll
        for (int r = 0; r < 4; ++r) {
            float v = rs[r];
            v += __shfl_xor(v, 1);
            v += __shfl_xor(v, 2);
            v += __shfl_xor(v, 4);
            v += __shfl_xor(v, 8);
            l_[r] = l_[r] * al[r] + v;
        }
#pragma unroll
        for (int d = 0; d < 8; ++d)
#pragma unroll
            for (int r = 0; r < 4; ++r) acc[d][r] *= al[r];

        // O += P V
#pragma unroll
        for (int kcp = 0; kcp < 4; ++kcp) {
            const bf16x8 pf = *(const bf16x8*)(Pl + l15 * PSTR + kcp * 32 + quad * 8);
#pragma unroll
            for (int db = 0; db < 8; ++db) {
                const bf16x8 vf = *(const bf16x8*)(Vtg + (size_t)(db * 16 + l15) * S_LEN
                                                   + k0 + kcp * 32 + quad * 8);
                acc[db] = mfma16(pf, vf, acc[db]);
            }
        }
    }

    // intra-block merge of 4 per-wave partials
    if (l15 == 0) {
#pragma unroll
        for (int r = 0; r < 4; ++r) {
            mlbuf[wv][quad * 4 + r][0] = m_[r];
            mlbuf[wv][quad * 4 + r][1] = l_[r];
        }
    }
    __syncthreads();   // zeros + mlbuf complete

#pragma unroll
    for (int r = 0; r < 4; ++r) {
        const int row = quad * 4 + r;
        float M = mlbuf[0][row][0];
#pragma unroll
        for (int w = 1; w < NWA; ++w) M = fmaxf(M, mlbuf[w][row][0]);
        const float be = exp2f(m_[r] - M);   // 0 for idle waves
        if (l15 == 0) atomicAdd(&mergeL[row], l_[r] * be);
#pragma unroll
        for (int d = 0; d < 8; ++d)
            atomicAdd(&mergeO[row * 132 + d * 16 + l15], acc[d][r] * be);
    }
    __syncthreads();

    // write partial: m[16] | l[16] | O[16][128]
    float* slot = Part + ((size_t)qt * 4 + chunk) * PARTSZ;
    if (tid < 16) {
        float M = mlbuf[0][tid][0];
#pragma unroll
        for (int w = 1; w < NWA; ++w) M = fmaxf(M, mlbuf[w][tid][0]);
        slot[tid] = M;
        slot[16 + tid] = mergeL[tid];
    }
#pragma unroll
    for (int j = tid; j < 512; j += 256) {
        const int row = j >> 5, c4 = j & 31;
        *(float4*)(slot + 32 + row * 128 + c4 * 4) =
            *(const float4*)&mergeO[row * 132 + c4 * 4];
    }
}

// ---------------------------------------------------------------------------
// Merge <=4 partials per q-tile, normalize, write output.
// ---------------------------------------------------------------------------
__global__ __launch_bounds__(128)
void flash_merge_kernel(const float* __restrict__ Part, float* __restrict__ Out) {
    __shared__ float Ms[16], Ls[16];
    const int qt = blockIdx.x;
    const int q0 = qt * 16;
    const int P  = (qt >> 7) + 1;
    const int tid = threadIdx.x;
    const float* base = Part + (size_t)qt * 4 * PARTSZ;

    if (tid < 16) {
        float M = -__builtin_inff();
        for (int p = 0; p < P; ++p) M = fmaxf(M, base[p * PARTSZ + tid]);
        float L = 0.f;
        for (int p = 0; p < P; ++p)
            L += base[p * PARTSZ + 16 + tid] * exp2f(base[p * PARTSZ + tid] - M);
        Ms[tid] = M; Ls[tid] = L;
    }
    __syncthreads();

    for (int row = 0; row < 16; ++row) {
        float o = 0.f;
        for (int p = 0; p < P; ++p) {
            const float sc = exp2f(base[p * PARTSZ + row] - Ms[row]);
            o += base[p * PARTSZ + 32 + row * 128 + tid] * sc;
        }
        Out[(size_t)(q0 + row) * DK + tid] = o / Ls[row];
    }
}

extern "C" void kernel_launch(void* const* d_in, const int* in_sizes, int n_in,
                              void* d_out, int out_size, void* d_ws, size_t ws_size,
                              hipStream_t stream) {
    const float* X  = (const float*)d_in[0];
    const float* Wq = (const float*)d_in[1];
    const float* Wk = (const float*)d_in[2];
    const float* Wv = (const float*)d_in[3];
    ushort* ws  = (ushort*)d_ws;
    ushort* Qb  = ws;                          // 8192x128 bf16 (pre-scaled)
    ushort* Kb  = ws + (size_t)S_LEN * DK;     // 8192x128 bf16
    ushort* Vtb = ws + 2 * (size_t)S_LEN * DK; // 128x8192 bf16 (transposed)
    _Float16* Xh = (_Float16*)(ws + 3 * (size_t)S_LEN * DK);  // 8192x1024 fp16
    _Float16* Wh = Xh + (size_t)S_LEN * DM;                   // 384x1024 fp16
    // Partials alias Xh/Wh (dead after proj_gemm): 512*4 slots * 2080 floats = 17.0 MB
    float* Part = (float*)Xh;
    float* Out = (float*)d_out;

    convert_kernel<<<1024, 256, 0, stream>>>(X, Wq, Wk, Wv, Xh, Wh);
    proj_gemm_kernel<<<dim3(64, 3), 256, 0, stream>>>(Xh, Wh, Qb, Kb, Vtb);
    flash_partial_kernel<<<1280, 256, 0, stream>>>(Qb, Kb, Vtb, Part);
    flash_merge_kernel<<<512, 128, 0, stream>>>(Part, Out);
}

// Round 7
// 333.601 us; speedup vs baseline: 1.0556x; 1.0556x over previous
//
#include <hip/hip_runtime.h>
#include <hip/hip_bf16.h>

#define S_LEN 8192
#define DM    1024
#define DK    128
#define NWA   4      // waves per flash_partial block
#define PSTR  136    // P LDS row stride in bf16 (2-way max bank aliasing)
#define PARTSZ 2080  // floats per partial slot: m[16] l[16] O[16*128]

typedef __attribute__((ext_vector_type(8))) short bf16x8;
typedef __attribute__((ext_vector_type(8))) _Float16 f16x8;
typedef __attribute__((ext_vector_type(4))) float f32x4;

__device__ __forceinline__ f32x4 mfma16(bf16x8 a, bf16x8 b, f32x4 c) {
    return __builtin_amdgcn_mfma_f32_16x16x32_bf16(a, b, c, 0, 0, 0);
}

// fp32 -> bf16 (RNE)
__device__ __forceinline__ ushort f2bf(float f) {
    unsigned u = __builtin_bit_cast(unsigned, f);
    u += 0x7FFFu + ((u >> 16) & 1u);
    return (ushort)(u >> 16);
}

// ---------------------------------------------------------------------------
// fp32 -> fp16 conversion of X (8192x1024) and Wq|Wk|Wv (each 128x1024).
// ---------------------------------------------------------------------------
__global__ __launch_bounds__(256, 1)
void convert_kernel(const float* __restrict__ X,
                    const float* __restrict__ Wq,
                    const float* __restrict__ Wk,
                    const float* __restrict__ Wv,
                    _Float16* __restrict__ Xh,
                    _Float16* __restrict__ Wh) {
    const int NX4 = S_LEN * DM / 4;
    const int NW4 = DK * DM / 4;
    const int total4 = NX4 + 3 * NW4;
    for (int i = blockIdx.x * 256 + threadIdx.x; i < total4; i += gridDim.x * 256) {
        const float4* src;
        _Float16* dst;
        int off;
        if (i < NX4) {
            src = (const float4*)X; dst = Xh; off = i;
        } else {
            const int w = i - NX4;
            const int which = w / NW4;
            off = w - which * NW4;
            src = (const float4*)(which == 0 ? Wq : (which == 1 ? Wk : Wv));
            dst = Wh + which * (DK * DM);
        }
        const float4 v = src[off];
        union { _Float16 h[4]; uint2 u; } p;
        p.h[0] = (_Float16)v.x; p.h[1] = (_Float16)v.y;
        p.h[2] = (_Float16)v.z; p.h[3] = (_Float16)v.w;
        *(uint2*)(dst + (size_t)off * 4) = p.u;
    }
}

// ---------------------------------------------------------------------------
// Projection GEMM (fp16 MFMA): C[8192x384] = Xh[8192x1024] @ Wh^T.
// ---------------------------------------------------------------------------
__global__ __launch_bounds__(256)
void proj_gemm_kernel(const _Float16* __restrict__ Xh,
                      const _Float16* __restrict__ Wh,
                      ushort* __restrict__ Qb,
                      ushort* __restrict__ Kb,
                      ushort* __restrict__ Vtb) {
    __shared__ _Float16 Ash[128 * 32];
    __shared__ _Float16 Bsh[128 * 32];

    const int tid  = threadIdx.x;
    const int lane = tid & 63;
    const int quad = lane >> 4;
    const int l15  = lane & 15;
    const int wv   = tid >> 6;
    const int wm   = wv & 1;
    const int wn   = wv >> 1;
    const int m0   = blockIdx.x * 128;
    const int nb   = blockIdx.y;
    const _Float16* Wbase = Wh + nb * (DK * DM);

    f32x4 acc[4][4];
#pragma unroll
    for (int mi = 0; mi < 4; ++mi)
#pragma unroll
        for (int ni = 0; ni < 4; ++ni) acc[mi][ni] = (f32x4){0.f, 0.f, 0.f, 0.f};

    for (int kk = 0; kk < DM; kk += 32) {
        __syncthreads();
#pragma unroll
        for (int s = tid; s < 512; s += 256) {
            const int row = s >> 2, sg = s & 3;
            __builtin_amdgcn_global_load_lds(
                (const __attribute__((address_space(1))) void*)(Xh + (size_t)(m0 + row) * DM + kk + sg * 8),
                (__attribute__((address_space(3))) void*)(Ash + s * 8), 16, 0, 0);
            __builtin_amdgcn_global_load_lds(
                (const __attribute__((address_space(1))) void*)(Wbase + (size_t)row * DM + kk + sg * 8),
                (__attribute__((address_space(3))) void*)(Bsh + s * 8), 16, 0, 0);
        }
        __syncthreads();

        f16x8 af[4], bf[4];
#pragma unroll
        for (int t = 0; t < 4; ++t) {
            af[t] = *(const f16x8*)(Ash + (wm * 64 + t * 16 + l15) * 32 + quad * 8);
            bf[t] = *(const f16x8*)(Bsh + (wn * 64 + t * 16 + l15) * 32 + quad * 8);
        }
#pragma unroll
        for (int mi = 0; mi < 4; ++mi)
#pragma unroll
            for (int ni = 0; ni < 4; ++ni)
                acc[mi][ni] = __builtin_amdgcn_mfma_f32_16x16x32_f16(af[mi], bf[ni], acc[mi][ni], 0, 0, 0);
    }

    if (nb == 2) {
#pragma unroll
        for (int mi = 0; mi < 4; ++mi)
#pragma unroll
            for (int ni = 0; ni < 4; ++ni) {
                const int n = wn * 64 + ni * 16 + l15;
                const int m = m0 + wm * 64 + mi * 16 + quad * 4;
                union { ushort h[4]; uint2 u; } p;
#pragma unroll
                for (int r = 0; r < 4; ++r) p.h[r] = f2bf(acc[mi][ni][r]);
                *(uint2*)(Vtb + (size_t)n * S_LEN + m) = p.u;
            }
    } else {
        ushort* Ob = (nb == 0) ? Qb : Kb;
        const float sc = (nb == 0) ? 0.088388347648318447f * 1.4426950408889634f : 1.0f;
#pragma unroll
        for (int mi = 0; mi < 4; ++mi)
#pragma unroll
            for (int ni = 0; ni < 4; ++ni) {
                const int n = wn * 64 + ni * 16 + l15;
#pragma unroll
                for (int r = 0; r < 4; ++r) {
                    const int m = m0 + wm * 64 + mi * 16 + quad * 4 + r;
                    Ob[(size_t)m * DK + n] = f2bf(acc[mi][ni][r] * sc);
                }
            }
    }
}

// ---------------------------------------------------------------------------
// Flash attention partials: split-K across blocks for occupancy.
// 1280 blocks x 256 thr (4 waves). Work item = (q-tile qt, chunk of k-tiles).
// launch_bounds(256,4): VGPR cap 128 >= ~92 needed -> NO SPILL (round-5 (256,5)
// capped lower and the allocator spilled to scratch: 155MB fetch/178MB write).
// ---------------------------------------------------------------------------
__global__ __launch_bounds__(256, 4)
void flash_partial_kernel(const ushort* __restrict__ Qg,
                          const ushort* __restrict__ Kg,
                          const ushort* __restrict__ Vtg,
                          float* __restrict__ Part) {
    __shared__ __align__(16) ushort Plds[NWA * 16 * PSTR];
    __shared__ __align__(16) float mergeO[16 * 132];
    __shared__ float mergeL[16];
    __shared__ float mlbuf[NWA][16][2];

    const int b = blockIdx.x;
    int qt, chunk, P;
    if (b < 128)      { qt = b;                  chunk = 0;            P = 1; }
    else if (b < 384) { qt = 128 + ((b - 128) >> 1); chunk = (b - 128) & 1; P = 2; }
    else if (b < 768) { qt = 256 + (b - 384) / 3;    chunk = (b - 384) % 3; P = 3; }
    else              { qt = 384 + ((b - 768) >> 2); chunk = (b - 768) & 3; P = 4; }

    const int q0    = qt * 16;
    const int nkt   = (q0 + 16 + 127) >> 7;
    const int kt_lo = (chunk * nkt) / P;
    const int kt_hi = ((chunk + 1) * nkt) / P;

    const int tid  = threadIdx.x;
    const int wv   = tid >> 6;
    const int lane = tid & 63;
    const int quad = lane >> 4;
    const int l15  = lane & 15;
    ushort* Pl = Plds + wv * 16 * PSTR;

    for (int i = tid; i < 16 * 132; i += 256) mergeO[i] = 0.f;
    if (tid < 16) mergeL[tid] = 0.f;

    // Q fragments (A layout), resident
    bf16x8 qf[4];
    {
        const ushort* qrow = Qg + (size_t)(q0 + l15) * DK + quad * 8;
#pragma unroll
        for (int kc = 0; kc < 4; ++kc) qf[kc] = *(const bf16x8*)(qrow + kc * 32);
    }

    float m_[4], l_[4];
#pragma unroll
    for (int r = 0; r < 4; ++r) { m_[r] = -__builtin_inff(); l_[r] = 0.f; }
    f32x4 acc[8];
#pragma unroll
    for (int d = 0; d < 8; ++d) acc[d] = (f32x4){0.f, 0.f, 0.f, 0.f};

    for (int kt = kt_lo + wv; kt < kt_hi; kt += NWA) {
        const int k0 = kt << 7;

        // S = Q K^T (16 x 128), C layout
        f32x4 Sr[8];
#pragma unroll
        for (int nb = 0; nb < 8; ++nb) {
            Sr[nb] = (f32x4){0.f, 0.f, 0.f, 0.f};
            const ushort* krow = Kg + (size_t)(k0 + nb * 16 + l15) * DK + quad * 8;
#pragma unroll
            for (int kc = 0; kc < 4; ++kc)
                Sr[nb] = mfma16(qf[kc], *(const bf16x8*)(krow + kc * 32), Sr[nb]);
        }

        // causal mask (diagonal tile only)
        if (k0 + 127 > q0) {
#pragma unroll
            for (int nb = 0; nb < 8; ++nb) {
                const int kg = k0 + nb * 16 + l15;
#pragma unroll
                for (int r = 0; r < 4; ++r)
                    if (kg > q0 + quad * 4 + r) Sr[nb][r] = -__builtin_inff();
            }
        }

        // online softmax (exp2 domain)
        float al[4], rs[4];
#pragma unroll
        for (int r = 0; r < 4; ++r) {
            float v = m_[r];
#pragma unroll
            for (int nb = 0; nb < 8; ++nb) v = fmaxf(v, Sr[nb][r]);
            v = fmaxf(v, __shfl_xor(v, 1));
            v = fmaxf(v, __shfl_xor(v, 2));
            v = fmaxf(v, __shfl_xor(v, 4));
            v = fmaxf(v, __shfl_xor(v, 8));
            al[r] = exp2f(m_[r] - v);
            m_[r] = v;
            rs[r] = 0.f;
        }
#pragma unroll
        for (int nb = 0; nb < 8; ++nb) {
#pragma unroll
            for (int r = 0; r < 4; ++r) {
                const float p = exp2f(Sr[nb][r] - m_[r]);
                rs[r] += p;
                Pl[(quad * 4 + r) * PSTR + nb * 16 + l15] = f2bf(p);
            }
        }
#pragma unroll
        for (int r = 0; r < 4; ++r) {
            float v = rs[r];
            v += __shfl_xor(v, 1);
            v += __shfl_xor(v, 2);
            v += __shfl_xor(v, 4);
            v += __shfl_xor(v, 8);
            l_[r] = l_[r] * al[r] + v;
        }
#pragma unroll
        for (int d = 0; d < 8; ++d)
#pragma unroll
            for (int r = 0; r < 4; ++r) acc[d][r] *= al[r];

        // O += P V
#pragma unroll
        for (int kcp = 0; kcp < 4; ++kcp) {
            const bf16x8 pf = *(const bf16x8*)(Pl + l15 * PSTR + kcp * 32 + quad * 8);
#pragma unroll
            for (int db = 0; db < 8; ++db) {
                const bf16x8 vf = *(const bf16x8*)(Vtg + (size_t)(db * 16 + l15) * S_LEN
                                                   + k0 + kcp * 32 + quad * 8);
                acc[db] = mfma16(pf, vf, acc[db]);
            }
        }
    }

    // intra-block merge of 4 per-wave partials
    if (l15 == 0) {
#pragma unroll
        for (int r = 0; r < 4; ++r) {
            mlbuf[wv][quad * 4 + r][0] = m_[r];
            mlbuf[wv][quad * 4 + r][1] = l_[r];
        }
    }
    __syncthreads();   // zeros + mlbuf complete

#pragma unroll
    for (int r = 0; r < 4; ++r) {
        const int row = quad * 4 + r;
        float M = mlbuf[0][row][0];
#pragma unroll
        for (int w = 1; w < NWA; ++w) M = fmaxf(M, mlbuf[w][row][0]);
        const float be = exp2f(m_[r] - M);   // 0 for idle waves
        if (l15 == 0) atomicAdd(&mergeL[row], l_[r] * be);
#pragma unroll
        for (int d = 0; d < 8; ++d)
            atomicAdd(&mergeO[row * 132 + d * 16 + l15], acc[d][r] * be);
    }
    __syncthreads();

    // write partial: m[16] | l[16] | O[16][128]
    float* slot = Part + ((size_t)qt * 4 + chunk) * PARTSZ;
    if (tid < 16) {
        float M = mlbuf[0][tid][0];
#pragma unroll
        for (int w = 1; w < NWA; ++w) M = fmaxf(M, mlbuf[w][tid][0]);
        slot[tid] = M;
        slot[16 + tid] = mergeL[tid];
    }
#pragma unroll
    for (int j = tid; j < 512; j += 256) {
        const int row = j >> 5, c4 = j & 31;
        *(float4*)(slot + 32 + row * 128 + c4 * 4) =
            *(const float4*)&mergeO[row * 132 + c4 * 4];
    }
}

// ---------------------------------------------------------------------------
// Merge <=4 partials per q-tile, normalize, write output.
// ---------------------------------------------------------------------------
__global__ __launch_bounds__(128)
void flash_merge_kernel(const float* __restrict__ Part, float* __restrict__ Out) {
    __shared__ float Ms[16], Ls[16];
    const int qt = blockIdx.x;
    const int q0 = qt * 16;
    const int P  = (qt >> 7) + 1;
    const int tid = threadIdx.x;
    const float* base = Part + (size_t)qt * 4 * PARTSZ;

    if (tid < 16) {
        float M = -__builtin_inff();
        for (int p = 0; p < P; ++p) M = fmaxf(M, base[p * PARTSZ + tid]);
        float L = 0.f;
        for (int p = 0; p < P; ++p)
            L += base[p * PARTSZ + 16 + tid] * exp2f(base[p * PARTSZ + tid] - M);
        Ms[tid] = M; Ls[tid] = L;
    }
    __syncthreads();

    for (int row = 0; row < 16; ++row) {
        float o = 0.f;
        for (int p = 0; p < P; ++p) {
            const float sc = exp2f(base[p * PARTSZ + row] - Ms[row]);
            o += base[p * PARTSZ + 32 + row * 128 + tid] * sc;
        }
        Out[(size_t)(q0 + row) * DK + tid] = o / Ls[row];
    }
}

extern "C" void kernel_launch(void* const* d_in, const int* in_sizes, int n_in,
                              void* d_out, int out_size, void* d_ws, size_t ws_size,
                              hipStream_t stream) {
    const float* X  = (const float*)d_in[0];
    const float* Wq = (const float*)d_in[1];
    const float* Wk = (const float*)d_in[2];
    const float* Wv = (const float*)d_in[3];
    ushort* ws  = (ushort*)d_ws;
    ushort* Qb  = ws;                          // 8192x128 bf16 (pre-scaled)
    ushort* Kb  = ws + (size_t)S_LEN * DK;     // 8192x128 bf16
    ushort* Vtb = ws + 2 * (size_t)S_LEN * DK; // 128x8192 bf16 (transposed)
    _Float16* Xh = (_Float16*)(ws + 3 * (size_t)S_LEN * DK);  // 8192x1024 fp16
    _Float16* Wh = Xh + (size_t)S_LEN * DM;                   // 384x1024 fp16
    // Partials alias Xh/Wh (dead after proj_gemm): 512*4 slots * 2080 floats = 17.0 MB
    float* Part = (float*)Xh;
    float* Out = (float*)d_out;

    convert_kernel<<<1024, 256, 0, stream>>>(X, Wq, Wk, Wv, Xh, Wh);
    proj_gemm_kernel<<<dim3(64, 3), 256, 0, stream>>>(Xh, Wh, Qb, Kb, Vtb);
    flash_partial_kernel<<<1280, 256, 0, stream>>>(Qb, Kb, Vtb, Part);
    flash_merge_kernel<<<512, 128, 0, stream>>>(Part, Out);
}

// Round 9
// 215.032 us; speedup vs baseline: 1.6377x; 1.5514x over previous
//
#include <hip/hip_runtime.h>
#include <hip/hip_bf16.h>

#define S_LEN 8192
#define DM    1024
#define DK    128
#define KSTR  136    // K LDS row stride (shorts): 2-way max bank aliasing
#define VSTR  72     // Vt LDS row stride (shorts)
#define PSTR2 72     // P LDS row stride (shorts)
#define SLOTD 1056   // dwords per partial slot: m[16] l[16] fp32 + O[16*128] fp16

typedef __attribute__((ext_vector_type(8))) short bf16x8;
typedef __attribute__((ext_vector_type(8))) _Float16 f16x8;
typedef __attribute__((ext_vector_type(4))) float f32x4;

__device__ __forceinline__ f32x4 mfma16(bf16x8 a, bf16x8 b, f32x4 c) {
    return __builtin_amdgcn_mfma_f32_16x16x32_bf16(a, b, c, 0, 0, 0);
}

// fp32 -> bf16 (RNE)
__device__ __forceinline__ ushort f2bf(float f) {
    unsigned u = __builtin_bit_cast(unsigned, f);
    u += 0x7FFFu + ((u >> 16) & 1u);
    return (ushort)(u >> 16);
}

__device__ __forceinline__ ushort f2h(float f) {
    return __builtin_bit_cast(ushort, (_Float16)f);
}

// ---------------------------------------------------------------------------
// fp32 -> fp16 conversion of X (8192x1024) and Wq|Wk|Wv (each 128x1024).
// ---------------------------------------------------------------------------
__global__ __launch_bounds__(256, 1)
void convert_kernel(const float* __restrict__ X,
                    const float* __restrict__ Wq,
                    const float* __restrict__ Wk,
                    const float* __restrict__ Wv,
                    _Float16* __restrict__ Xh,
                    _Float16* __restrict__ Wh) {
    const int NX4 = S_LEN * DM / 4;
    const int NW4 = DK * DM / 4;
    const int total4 = NX4 + 3 * NW4;
    for (int i = blockIdx.x * 256 + threadIdx.x; i < total4; i += gridDim.x * 256) {
        const float4* src;
        _Float16* dst;
        int off;
        if (i < NX4) {
            src = (const float4*)X; dst = Xh; off = i;
        } else {
            const int w = i - NX4;
            const int which = w / NW4;
            off = w - which * NW4;
            src = (const float4*)(which == 0 ? Wq : (which == 1 ? Wk : Wv));
            dst = Wh + which * (DK * DM);
        }
        const float4 v = src[off];
        union { _Float16 h[4]; uint2 u; } p;
        p.h[0] = (_Float16)v.x; p.h[1] = (_Float16)v.y;
        p.h[2] = (_Float16)v.z; p.h[3] = (_Float16)v.w;
        *(uint2*)(dst + (size_t)off * 4) = p.u;
    }
}

// ---------------------------------------------------------------------------
// Projection GEMM (fp16 MFMA): C[8192x384] = Xh[8192x1024] @ Wh^T.
// ---------------------------------------------------------------------------
__global__ __launch_bounds__(256)
void proj_gemm_kernel(const _Float16* __restrict__ Xh,
                      const _Float16* __restrict__ Wh,
                      ushort* __restrict__ Qb,
                      ushort* __restrict__ Kb,
                      ushort* __restrict__ Vtb) {
    __shared__ _Float16 Ash[128 * 32];
    __shared__ _Float16 Bsh[128 * 32];

    const int tid  = threadIdx.x;
    const int lane = tid & 63;
    const int quad = lane >> 4;
    const int l15  = lane & 15;
    const int wv   = tid >> 6;
    const int wm   = wv & 1;
    const int wn   = wv >> 1;
    const int m0   = blockIdx.x * 128;
    const int nb   = blockIdx.y;
    const _Float16* Wbase = Wh + nb * (DK * DM);

    f32x4 acc[4][4];
#pragma unroll
    for (int mi = 0; mi < 4; ++mi)
#pragma unroll
        for (int ni = 0; ni < 4; ++ni) acc[mi][ni] = (f32x4){0.f, 0.f, 0.f, 0.f};

    for (int kk = 0; kk < DM; kk += 32) {
        __syncthreads();
#pragma unroll
        for (int s = tid; s < 512; s += 256) {
            const int row = s >> 2, sg = s & 3;
            __builtin_amdgcn_global_load_lds(
                (const __attribute__((address_space(1))) void*)(Xh + (size_t)(m0 + row) * DM + kk + sg * 8),
                (__attribute__((address_space(3))) void*)(Ash + s * 8), 16, 0, 0);
            __builtin_amdgcn_global_load_lds(
                (const __attribute__((address_space(1))) void*)(Wbase + (size_t)row * DM + kk + sg * 8),
                (__attribute__((address_space(3))) void*)(Bsh + s * 8), 16, 0, 0);
        }
        __syncthreads();

        f16x8 af[4], bf[4];
#pragma unroll
        for (int t = 0; t < 4; ++t) {
            af[t] = *(const f16x8*)(Ash + (wm * 64 + t * 16 + l15) * 32 + quad * 8);
            bf[t] = *(const f16x8*)(Bsh + (wn * 64 + t * 16 + l15) * 32 + quad * 8);
        }
#pragma unroll
        for (int mi = 0; mi < 4; ++mi)
#pragma unroll
            for (int ni = 0; ni < 4; ++ni)
                acc[mi][ni] = __builtin_amdgcn_mfma_f32_16x16x32_f16(af[mi], bf[ni], acc[mi][ni], 0, 0, 0);
    }

    if (nb == 2) {
#pragma unroll
        for (int mi = 0; mi < 4; ++mi)
#pragma unroll
            for (int ni = 0; ni < 4; ++ni) {
                const int n = wn * 64 + ni * 16 + l15;
                const int m = m0 + wm * 64 + mi * 16 + quad * 4;
                union { ushort h[4]; uint2 u; } p;
#pragma unroll
                for (int r = 0; r < 4; ++r) p.h[r] = f2bf(acc[mi][ni][r]);
                *(uint2*)(Vtb + (size_t)n * S_LEN + m) = p.u;
            }
    } else {
        ushort* Ob = (nb == 0) ? Qb : Kb;
        const float sc = (nb == 0) ? 0.088388347648318447f * 1.4426950408889634f : 1.0f;
#pragma unroll
        for (int mi = 0; mi < 4; ++mi)
#pragma unroll
            for (int ni = 0; ni < 4; ++ni) {
                const int n = wn * 64 + ni * 16 + l15;
#pragma unroll
                for (int r = 0; r < 4; ++r) {
                    const int m = m0 + wm * 64 + mi * 16 + quad * 4 + r;
                    Ob[(size_t)m * DK + n] = f2bf(acc[mi][ni][r] * sc);
                }
            }
    }
}

// ---------------------------------------------------------------------------
// Flash attention partials, LDS-staged (m97 skeleton).
// Block = 4 waves = 64 q-rows (wave w owns rows qb*64+16w.. , private m/l/acc
// -> no intra-block merge). K-loop: stage K(64x128)+Vt(128x64) tiles in padded
// LDS shared by all 4 waves, 2 barriers/tile. Grid = (qb, chunk): group
// g=qb>>4 has g+1 chunks (<=16 tiles each) -> 576 blocks, balanced.
// Partial slot (per 16-row q-tile x chunk): m[16],l[16] fp32 + O fp16.
// ---------------------------------------------------------------------------
__global__ __launch_bounds__(256, 3)
void flash_partial_kernel(const ushort* __restrict__ Qg,
                          const ushort* __restrict__ Kg,
                          const ushort* __restrict__ Vtg,
                          float* __restrict__ Part) {
    __shared__ __align__(16) ushort Ks [64 * KSTR];    // 17408 B
    __shared__ __align__(16) ushort Vts[128 * VSTR];   // 18432 B
    __shared__ __align__(16) ushort PlA[4 * 16 * PSTR2]; // 9216 B

    // decode (qb, chunk): group g has 16*(g+1) blocks, cumulative 8g(g+1)
    const int b = blockIdx.x;
    int g = 0;
    while (b >= 8 * (g + 1) * (g + 2)) ++g;
    const int idx   = b - 8 * g * (g + 1);
    const int qb    = 16 * g + idx / (g + 1);
    const int chunk = idx % (g + 1);
    const int nkt   = qb + 1;                   // 64-key tiles for this q-block
    const int kt_lo = chunk * nkt / (g + 1);
    const int kt_hi = (chunk + 1) * nkt / (g + 1);

    const int tid  = threadIdx.x;
    const int wv   = tid >> 6;
    const int lane = tid & 63;
    const int quad = lane >> 4;
    const int l15  = lane & 15;
    const int q0w  = qb * 64 + wv * 16;         // wave's first q-row
    ushort* Pl = PlA + wv * 16 * PSTR2;

    // Q fragments (A layout), resident
    bf16x8 qf[4];
    {
        const ushort* qrow = Qg + (size_t)(q0w + l15) * DK + quad * 8;
#pragma unroll
        for (int kc = 0; kc < 4; ++kc) qf[kc] = *(const bf16x8*)(qrow + kc * 32);
    }

    float m_[4], l_[4];
#pragma unroll
    for (int r = 0; r < 4; ++r) { m_[r] = -__builtin_inff(); l_[r] = 0.f; }
    f32x4 acc[8];
#pragma unroll
    for (int d = 0; d < 8; ++d) acc[d] = (f32x4){0.f, 0.f, 0.f, 0.f};

    for (int kt = kt_lo; kt < kt_hi; ++kt) {
        const int k0 = kt * 64;

        __syncthreads();   // previous tile's frag reads complete
        // stage K tile (64 rows x 128 shorts = 1024 16B-chunks, 16/row)
        // and Vt tile (128 rows x 64 shorts = 1024 chunks, 8/row)
#pragma unroll
        for (int c = tid; c < 2048; c += 256) {
            if (c < 1024) {
                const int row = c >> 4, ch = c & 15;
                *(bf16x8*)(Ks + row * KSTR + ch * 8) =
                    *(const bf16x8*)(Kg + (size_t)(k0 + row) * DK + ch * 8);
            } else {
                const int cc = c - 1024;
                const int row = cc >> 3, ch = cc & 7;
                *(bf16x8*)(Vts + row * VSTR + ch * 8) =
                    *(const bf16x8*)(Vtg + (size_t)row * S_LEN + k0 + ch * 8);
            }
        }
        __syncthreads();   // staging visible to all waves

        if (k0 > q0w + 15) continue;   // tile fully masked for this wave (uniform)

        // ---- S = Q K^T (16 x 64), B-frags from LDS ----
        f32x4 Sr[4];
#pragma unroll
        for (int nb = 0; nb < 4; ++nb) {
            Sr[nb] = (f32x4){0.f, 0.f, 0.f, 0.f};
            const ushort* kb = Ks + (nb * 16 + l15) * KSTR + quad * 8;
#pragma unroll
            for (int kc = 0; kc < 4; ++kc)
                Sr[nb] = mfma16(qf[kc], *(const bf16x8*)(kb + kc * 32), Sr[nb]);
        }

        // ---- causal mask (diagonal tile only) ----
        if (k0 + 63 > q0w) {
#pragma unroll
            for (int nb = 0; nb < 4; ++nb) {
                const int kg = k0 + nb * 16 + l15;
#pragma unroll
                for (int r = 0; r < 4; ++r)
                    if (kg > q0w + quad * 4 + r) Sr[nb][r] = -__builtin_inff();
            }
        }

        // ---- online softmax (exp2 domain) ----
        float al[4], rs[4];
#pragma unroll
        for (int r = 0; r < 4; ++r) {
            float v = m_[r];
#pragma unroll
            for (int nb = 0; nb < 4; ++nb) v = fmaxf(v, Sr[nb][r]);
            v = fmaxf(v, __shfl_xor(v, 1));
            v = fmaxf(v, __shfl_xor(v, 2));
            v = fmaxf(v, __shfl_xor(v, 4));
            v = fmaxf(v, __shfl_xor(v, 8));
            al[r] = exp2f(m_[r] - v);
            m_[r] = v;
            rs[r] = 0.f;
        }
#pragma unroll
        for (int nb = 0; nb < 4; ++nb) {
#pragma unroll
            for (int r = 0; r < 4; ++r) {
                const float p = exp2f(Sr[nb][r] - m_[r]);
                rs[r] += p;
                Pl[(quad * 4 + r) * PSTR2 + nb * 16 + l15] = f2bf(p);
            }
        }
#pragma unroll
        for (int r = 0; r < 4; ++r) {
            float v = rs[r];
            v += __shfl_xor(v, 1);
            v += __shfl_xor(v, 2);
            v += __shfl_xor(v, 4);
            v += __shfl_xor(v, 8);
            l_[r] = l_[r] * al[r] + v;
        }
#pragma unroll
        for (int d = 0; d < 8; ++d)
#pragma unroll
            for (int r = 0; r < 4; ++r) acc[d][r] *= al[r];

        // ---- O += P V (A-frag from wave-private Pl, B-frag from Vt LDS) ----
#pragma unroll
        for (int kcp = 0; kcp < 2; ++kcp) {
            const bf16x8 pf = *(const bf16x8*)(Pl + l15 * PSTR2 + kcp * 32 + quad * 8);
#pragma unroll
            for (int db = 0; db < 8; ++db) {
                const bf16x8 vf = *(const bf16x8*)(Vts + (db * 16 + l15) * VSTR + kcp * 32 + quad * 8);
                acc[db] = mfma16(pf, vf, acc[db]);
            }
        }
    }

    // ---- write partial slot (wave-private, no merge needed) ----
    const int qt16 = qb * 4 + wv;
    float* slot = Part + (size_t)(qt16 * 8 + chunk) * SLOTD;
    if (l15 == 0) {
#pragma unroll
        for (int r = 0; r < 4; ++r) {
            slot[quad * 4 + r]      = m_[r];
            slot[16 + quad * 4 + r] = l_[r];
        }
    }
    // O as fp16: pair lanes (l15 even/odd -> dims d, d+1) into one dword
    uint* slotO = (uint*)(slot + 32);
#pragma unroll
    for (int d = 0; d < 8; ++d)
#pragma unroll
        for (int r = 0; r < 4; ++r) {
            const float v  = acc[d][r];
            const float vp = __shfl_xor(v, 1);
            if ((l15 & 1) == 0) {
                const int row = quad * 4 + r;
                const uint u = (uint)f2h(v) | ((uint)f2h(vp) << 16);
                slotO[(row * 128 + d * 16 + l15) >> 1] = u;
            }
        }
}

// ---------------------------------------------------------------------------
// Merge <=8 partials per 16-row q-tile, normalize, write output.
// ---------------------------------------------------------------------------
__global__ __launch_bounds__(128)
void flash_merge_kernel(const float* __restrict__ Part, float* __restrict__ Out) {
    __shared__ float Ms[16], Ls[16];
    const int qt = blockIdx.x;
    const int q0 = qt * 16;
    const int P  = (qt >> 6) + 1;     // chunks for this q-tile's 64-row block
    const int tid = threadIdx.x;
    const float* base = Part + (size_t)qt * 8 * SLOTD;

    if (tid < 16) {
        float M = -__builtin_inff();
        for (int p = 0; p < P; ++p) M = fmaxf(M, base[p * SLOTD + tid]);
        float L = 0.f;
        for (int p = 0; p < P; ++p)
            L += base[p * SLOTD + 16 + tid] * exp2f(base[p * SLOTD + tid] - M);
        Ms[tid] = M; Ls[tid] = L;
    }
    __syncthreads();

    for (int row = 0; row < 16; ++row) {
        float o = 0.f;
        for (int p = 0; p < P; ++p) {
            const float sc = exp2f(base[p * SLOTD + row] - Ms[row]);
            const ushort h = ((const ushort*)(base + p * SLOTD + 32))[row * 128 + tid];
            o += (float)__builtin_bit_cast(_Float16, h) * sc;
        }
        Out[(size_t)(q0 + row) * DK + tid] = o / Ls[row];
    }
}

extern "C" void kernel_launch(void* const* d_in, const int* in_sizes, int n_in,
                              void* d_out, int out_size, void* d_ws, size_t ws_size,
                              hipStream_t stream) {
    const float* X  = (const float*)d_in[0];
    const float* Wq = (const float*)d_in[1];
    const float* Wk = (const float*)d_in[2];
    const float* Wv = (const float*)d_in[3];
    ushort* ws  = (ushort*)d_ws;
    ushort* Qb  = ws;                          // 8192x128 bf16 (pre-scaled)
    ushort* Kb  = ws + (size_t)S_LEN * DK;     // 8192x128 bf16
    ushort* Vtb = ws + 2 * (size_t)S_LEN * DK; // 128x8192 bf16 (transposed)
    _Float16* Xh = (_Float16*)(ws + 3 * (size_t)S_LEN * DK);  // 8192x1024 fp16
    _Float16* Wh = Xh + (size_t)S_LEN * DM;                   // 384x1024 fp16
    // Partials alias Xh/Wh (dead after proj_gemm): 4096 slots * 4224 B = 16.5 MiB
    float* Part = (float*)Xh;
    float* Out = (float*)d_out;

    convert_kernel<<<1024, 256, 0, stream>>>(X, Wq, Wk, Wv, Xh, Wh);
    proj_gemm_kernel<<<dim3(64, 3), 256, 0, stream>>>(Xh, Wh, Qb, Kb, Vtb);
    flash_partial_kernel<<<576, 256, 0, stream>>>(Qb, Kb, Vtb, Part);
    flash_merge_kernel<<<512, 128, 0, stream>>>(Part, Out);
}

// Round 10
// 197.948 us; speedup vs baseline: 1.7790x; 1.0863x over previous
//
#include <hip/hip_runtime.h>
#include <hip/hip_bf16.h>

#define S_LEN 8192
#define DM    1024
#define DK    128
#define KSTR  136    // K LDS row stride (shorts): 2-way max bank aliasing
#define VSTR  72     // Vt LDS row stride (shorts)
#define PSTR2 72     // P LDS row stride (shorts)
#define SLOTD 1056   // dwords per partial slot: m[16] l[16] fp32 + O[16*128] fp16

typedef __attribute__((ext_vector_type(8))) short bf16x8;
typedef __attribute__((ext_vector_type(8))) _Float16 f16x8;
typedef __attribute__((ext_vector_type(4))) float f32x4;

__device__ __forceinline__ f32x4 mfma16(bf16x8 a, bf16x8 b, f32x4 c) {
    return __builtin_amdgcn_mfma_f32_16x16x32_bf16(a, b, c, 0, 0, 0);
}

// fp32 -> bf16 (RNE)
__device__ __forceinline__ ushort f2bf(float f) {
    unsigned u = __builtin_bit_cast(unsigned, f);
    u += 0x7FFFu + ((u >> 16) & 1u);
    return (ushort)(u >> 16);
}

__device__ __forceinline__ ushort f2h(float f) {
    return __builtin_bit_cast(ushort, (_Float16)f);
}

// ---------------------------------------------------------------------------
// fp32 -> fp16 conversion of X (8192x1024) and Wq|Wk|Wv (each 128x1024).
// ---------------------------------------------------------------------------
__global__ __launch_bounds__(256, 1)
void convert_kernel(const float* __restrict__ X,
                    const float* __restrict__ Wq,
                    const float* __restrict__ Wk,
                    const float* __restrict__ Wv,
                    _Float16* __restrict__ Xh,
                    _Float16* __restrict__ Wh) {
    const int NX4 = S_LEN * DM / 4;
    const int NW4 = DK * DM / 4;
    const int total4 = NX4 + 3 * NW4;
    for (int i = blockIdx.x * 256 + threadIdx.x; i < total4; i += gridDim.x * 256) {
        const float4* src;
        _Float16* dst;
        int off;
        if (i < NX4) {
            src = (const float4*)X; dst = Xh; off = i;
        } else {
            const int w = i - NX4;
            const int which = w / NW4;
            off = w - which * NW4;
            src = (const float4*)(which == 0 ? Wq : (which == 1 ? Wk : Wv));
            dst = Wh + which * (DK * DM);
        }
        const float4 v = src[off];
        union { _Float16 h[4]; uint2 u; } p;
        p.h[0] = (_Float16)v.x; p.h[1] = (_Float16)v.y;
        p.h[2] = (_Float16)v.z; p.h[3] = (_Float16)v.w;
        *(uint2*)(dst + (size_t)off * 4) = p.u;
    }
}

// ---------------------------------------------------------------------------
// Projection GEMM (fp16 MFMA): C[8192x384] = Xh[8192x1024] @ Wh^T.
// BM=64 (was 128): grid (128,3)=384 blocks -> 1.5 blocks/CU for latency hiding
// (192 blocks was 0.75/CU). 4 waves, each 32x64 (2x4 accs).
// ---------------------------------------------------------------------------
__global__ __launch_bounds__(256)
void proj_gemm_kernel(const _Float16* __restrict__ Xh,
                      const _Float16* __restrict__ Wh,
                      ushort* __restrict__ Qb,
                      ushort* __restrict__ Kb,
                      ushort* __restrict__ Vtb) {
    __shared__ _Float16 Ash[64 * 32];    // 4 KB
    __shared__ _Float16 Bsh[128 * 32];   // 8 KB

    const int tid  = threadIdx.x;
    const int lane = tid & 63;
    const int quad = lane >> 4;
    const int l15  = lane & 15;
    const int wv   = tid >> 6;
    const int wm   = wv & 1;    // m-half (32 rows)
    const int wn   = wv >> 1;   // n-half (64 cols)
    const int m0   = blockIdx.x * 64;
    const int nb   = blockIdx.y;
    const _Float16* Wbase = Wh + nb * (DK * DM);

    f32x4 acc[2][4];
#pragma unroll
    for (int mi = 0; mi < 2; ++mi)
#pragma unroll
        for (int ni = 0; ni < 4; ++ni) acc[mi][ni] = (f32x4){0.f, 0.f, 0.f, 0.f};

    for (int kk = 0; kk < DM; kk += 32) {
        __syncthreads();
        // A: 64 rows x 4 chunks = 256; B: 128 rows x 4 chunks = 512; total 768
#pragma unroll
        for (int s = tid; s < 768; s += 256) {
            if (s < 256) {
                const int row = s >> 2, sg = s & 3;
                __builtin_amdgcn_global_load_lds(
                    (const __attribute__((address_space(1))) void*)(Xh + (size_t)(m0 + row) * DM + kk + sg * 8),
                    (__attribute__((address_space(3))) void*)(Ash + s * 8), 16, 0, 0);
            } else {
                const int t = s - 256;
                const int row = t >> 2, sg = t & 3;
                __builtin_amdgcn_global_load_lds(
                    (const __attribute__((address_space(1))) void*)(Wbase + (size_t)row * DM + kk + sg * 8),
                    (__attribute__((address_space(3))) void*)(Bsh + t * 8), 16, 0, 0);
            }
        }
        __syncthreads();

        f16x8 af[2], bf[4];
#pragma unroll
        for (int t = 0; t < 2; ++t)
            af[t] = *(const f16x8*)(Ash + (wm * 32 + t * 16 + l15) * 32 + quad * 8);
#pragma unroll
        for (int t = 0; t < 4; ++t)
            bf[t] = *(const f16x8*)(Bsh + (wn * 64 + t * 16 + l15) * 32 + quad * 8);
#pragma unroll
        for (int mi = 0; mi < 2; ++mi)
#pragma unroll
            for (int ni = 0; ni < 4; ++ni)
                acc[mi][ni] = __builtin_amdgcn_mfma_f32_16x16x32_f16(af[mi], bf[ni], acc[mi][ni], 0, 0, 0);
    }

    if (nb == 2) {
#pragma unroll
        for (int mi = 0; mi < 2; ++mi)
#pragma unroll
            for (int ni = 0; ni < 4; ++ni) {
                const int n = wn * 64 + ni * 16 + l15;
                const int m = m0 + wm * 32 + mi * 16 + quad * 4;
                union { ushort h[4]; uint2 u; } p;
#pragma unroll
                for (int r = 0; r < 4; ++r) p.h[r] = f2bf(acc[mi][ni][r]);
                *(uint2*)(Vtb + (size_t)n * S_LEN + m) = p.u;
            }
    } else {
        ushort* Ob = (nb == 0) ? Qb : Kb;
        const float sc = (nb == 0) ? 0.088388347648318447f * 1.4426950408889634f : 1.0f;
#pragma unroll
        for (int mi = 0; mi < 2; ++mi)
#pragma unroll
            for (int ni = 0; ni < 4; ++ni) {
                const int n = wn * 64 + ni * 16 + l15;
#pragma unroll
                for (int r = 0; r < 4; ++r) {
                    const int m = m0 + wm * 32 + mi * 16 + quad * 4 + r;
                    Ob[(size_t)m * DK + n] = f2bf(acc[mi][ni][r] * sc);
                }
            }
    }
}

// ---------------------------------------------------------------------------
// Flash attention partials, LDS-staged + register prefetch + sum-via-MFMA.
// Block = 4 waves = 64 q-rows. Grid = (qb, chunk), 576 blocks.
// Per tile: prefetch next K/V into regs (global latency hidden under MFMA),
// row-max via 4 shuffles, row-sum via extra MFMA with B=ones (no shuffles).
// ---------------------------------------------------------------------------
__global__ __launch_bounds__(256, 3)
void flash_partial_kernel(const ushort* __restrict__ Qg,
                          const ushort* __restrict__ Kg,
                          const ushort* __restrict__ Vtg,
                          float* __restrict__ Part) {
    __shared__ __align__(16) ushort Ks [64 * KSTR];      // 17408 B
    __shared__ __align__(16) ushort Vts[128 * VSTR];     // 18432 B
    __shared__ __align__(16) ushort PlA[4 * 16 * PSTR2]; // 9216 B

    // decode (qb, chunk): group g has 16*(g+1) blocks, cumulative 8g(g+1)
    const int b = blockIdx.x;
    int g = 0;
    while (b >= 8 * (g + 1) * (g + 2)) ++g;
    const int idx   = b - 8 * g * (g + 1);
    const int qb    = 16 * g + idx / (g + 1);
    const int chunk = idx % (g + 1);
    const int nkt   = qb + 1;
    const int kt_lo = chunk * nkt / (g + 1);
    const int kt_hi = (chunk + 1) * nkt / (g + 1);

    const int tid  = threadIdx.x;
    const int wv   = tid >> 6;
    const int lane = tid & 63;
    const int quad = lane >> 4;
    const int l15  = lane & 15;
    const int q0w  = qb * 64 + wv * 16;
    ushort* Pl = PlA + wv * 16 * PSTR2;

    // Q fragments (A layout), resident
    bf16x8 qf[4];
    {
        const ushort* qrow = Qg + (size_t)(q0w + l15) * DK + quad * 8;
#pragma unroll
        for (int kc = 0; kc < 4; ++kc) qf[kc] = *(const bf16x8*)(qrow + kc * 32);
    }

    const bf16x8 ones = {(short)0x3F80, (short)0x3F80, (short)0x3F80, (short)0x3F80,
                         (short)0x3F80, (short)0x3F80, (short)0x3F80, (short)0x3F80};

    float m_[4], l_[4];
#pragma unroll
    for (int r = 0; r < 4; ++r) { m_[r] = -__builtin_inff(); l_[r] = 0.f; }
    f32x4 acc[8];
#pragma unroll
    for (int d = 0; d < 8; ++d) acc[d] = (f32x4){0.f, 0.f, 0.f, 0.f};

    // staging assignment: thread covers chunks c = tid + i*256, i<8
    // c < 1024: K row c>>4, chunk c&15; else: Vt row (c-1024)>>3, chunk &7
    bf16x8 stg[8];
#define LOAD_TILE(K0)                                                          \
    {                                                                          \
        const int k0_ = (K0);                                                  \
        _Pragma("unroll")                                                      \
        for (int i = 0; i < 8; ++i) {                                          \
            const int c = tid + (i << 8);                                      \
            if (c < 1024) {                                                    \
                const int row = c >> 4, ch = c & 15;                           \
                stg[i] = *(const bf16x8*)(Kg + (size_t)(k0_ + row) * DK + ch * 8); \
            } else {                                                           \
                const int cc = c - 1024;                                       \
                const int row = cc >> 3, ch = cc & 7;                          \
                stg[i] = *(const bf16x8*)(Vtg + (size_t)row * S_LEN + k0_ + ch * 8); \
            }                                                                  \
        }                                                                      \
    }

    LOAD_TILE(kt_lo * 64)

    for (int kt = kt_lo; kt < kt_hi; ++kt) {
        const int k0 = kt * 64;

        __syncthreads();   // previous tile's frag reads complete
#pragma unroll
        for (int i = 0; i < 8; ++i) {
            const int c = tid + (i << 8);
            if (c < 1024) {
                const int row = c >> 4, ch = c & 15;
                *(bf16x8*)(Ks + row * KSTR + ch * 8) = stg[i];
            } else {
                const int cc = c - 1024;
                const int row = cc >> 3, ch = cc & 7;
                *(bf16x8*)(Vts + row * VSTR + ch * 8) = stg[i];
            }
        }
        if (kt + 1 < kt_hi) LOAD_TILE((kt + 1) * 64)   // prefetch into regs
        __syncthreads();   // staging visible to all waves

        // ---- S = Q K^T (16 x 64), B-frags from LDS ----
        f32x4 Sr[4];
#pragma unroll
        for (int nb = 0; nb < 4; ++nb) {
            Sr[nb] = (f32x4){0.f, 0.f, 0.f, 0.f};
            const ushort* kb = Ks + (nb * 16 + l15) * KSTR + quad * 8;
#pragma unroll
            for (int kc = 0; kc < 4; ++kc)
                Sr[nb] = mfma16(qf[kc], *(const bf16x8*)(kb + kc * 32), Sr[nb]);
        }

        // ---- causal mask (diagonal tile only) ----
        if (k0 + 63 > q0w) {
#pragma unroll
            for (int nb = 0; nb < 4; ++nb) {
                const int kg = k0 + nb * 16 + l15;
#pragma unroll
                for (int r = 0; r < 4; ++r)
                    if (kg > q0w + quad * 4 + r) Sr[nb][r] = -__builtin_inff();
            }
        }

        // ---- online softmax: row max via shuffles, P to LDS ----
        float al[4];
#pragma unroll
        for (int r = 0; r < 4; ++r) {
            float v = m_[r];
#pragma unroll
            for (int nb = 0; nb < 4; ++nb) v = fmaxf(v, Sr[nb][r]);
            v = fmaxf(v, __shfl_xor(v, 1));
            v = fmaxf(v, __shfl_xor(v, 2));
            v = fmaxf(v, __shfl_xor(v, 4));
            v = fmaxf(v, __shfl_xor(v, 8));
            al[r] = exp2f(m_[r] - v);
            m_[r] = v;
        }
#pragma unroll
        for (int nb = 0; nb < 4; ++nb) {
#pragma unroll
            for (int r = 0; r < 4; ++r) {
                const float p = exp2f(Sr[nb][r] - m_[r]);
                Pl[(quad * 4 + r) * PSTR2 + nb * 16 + l15] = f2bf(p);
            }
        }
#pragma unroll
        for (int d = 0; d < 8; ++d)
#pragma unroll
            for (int r = 0; r < 4; ++r) acc[d][r] *= al[r];

        // ---- O += P V; row-sum of P via MFMA with B=ones ----
        f32x4 sacc = (f32x4){0.f, 0.f, 0.f, 0.f};
#pragma unroll
        for (int kcp = 0; kcp < 2; ++kcp) {
            const bf16x8 pf = *(const bf16x8*)(Pl + l15 * PSTR2 + kcp * 32 + quad * 8);
            sacc = mfma16(pf, ones, sacc);
#pragma unroll
            for (int db = 0; db < 8; ++db) {
                const bf16x8 vf = *(const bf16x8*)(Vts + (db * 16 + l15) * VSTR + kcp * 32 + quad * 8);
                acc[db] = mfma16(pf, vf, acc[db]);
            }
        }
#pragma unroll
        for (int r = 0; r < 4; ++r) l_[r] = l_[r] * al[r] + sacc[r];
    }
#undef LOAD_TILE

    // ---- write partial slot (wave-private, no merge needed) ----
    const int qt16 = qb * 4 + wv;
    float* slot = Part + (size_t)(qt16 * 8 + chunk) * SLOTD;
    if (l15 == 0) {
#pragma unroll
        for (int r = 0; r < 4; ++r) {
            slot[quad * 4 + r]      = m_[r];
            slot[16 + quad * 4 + r] = l_[r];
        }
    }
    // O as fp16: pair lanes (l15 even/odd -> dims d, d+1) into one dword
    uint* slotO = (uint*)(slot + 32);
#pragma unroll
    for (int d = 0; d < 8; ++d)
#pragma unroll
        for (int r = 0; r < 4; ++r) {
            const float v  = acc[d][r];
            const float vp = __shfl_xor(v, 1);
            if ((l15 & 1) == 0) {
                const int row = quad * 4 + r;
                const uint u = (uint)f2h(v) | ((uint)f2h(vp) << 16);
                slotO[(row * 128 + d * 16 + l15) >> 1] = u;
            }
        }
}

// ---------------------------------------------------------------------------
// Merge <=8 partials per 16-row q-tile, normalize, write output.
// ---------------------------------------------------------------------------
__global__ __launch_bounds__(128)
void flash_merge_kernel(const float* __restrict__ Part, float* __restrict__ Out) {
    __shared__ float Ms[16], Ls[16];
    const int qt = blockIdx.x;
    const int q0 = qt * 16;
    const int P  = (qt >> 6) + 1;
    const int tid = threadIdx.x;
    const float* base = Part + (size_t)qt * 8 * SLOTD;

    if (tid < 16) {
        float M = -__builtin_inff();
        for (int p = 0; p < P; ++p) M = fmaxf(M, base[p * SLOTD + tid]);
        float L = 0.f;
        for (int p = 0; p < P; ++p)
            L += base[p * SLOTD + 16 + tid] * exp2f(base[p * SLOTD + tid] - M);
        Ms[tid] = M; Ls[tid] = L;
    }
    __syncthreads();

    for (int row = 0; row < 16; ++row) {
        float o = 0.f;
        for (int p = 0; p < P; ++p) {
            const float sc = exp2f(base[p * SLOTD + row] - Ms[row]);
            const ushort h = ((const ushort*)(base + p * SLOTD + 32))[row * 128 + tid];
            o += (float)__builtin_bit_cast(_Float16, h) * sc;
        }
        Out[(size_t)(q0 + row) * DK + tid] = o / Ls[row];
    }
}

extern "C" void kernel_launch(void* const* d_in, const int* in_sizes, int n_in,
                              void* d_out, int out_size, void* d_ws, size_t ws_size,
                              hipStream_t stream) {
    const float* X  = (const float*)d_in[0];
    const float* Wq = (const float*)d_in[1];
    const float* Wk = (const float*)d_in[2];
    const float* Wv = (const float*)d_in[3];
    ushort* ws  = (ushort*)d_ws;
    ushort* Qb  = ws;                          // 8192x128 bf16 (pre-scaled)
    ushort* Kb  = ws + (size_t)S_LEN * DK;     // 8192x128 bf16
    ushort* Vtb = ws + 2 * (size_t)S_LEN * DK; // 128x8192 bf16 (transposed)
    _Float16* Xh = (_Float16*)(ws + 3 * (size_t)S_LEN * DK);  // 8192x1024 fp16
    _Float16* Wh = Xh + (size_t)S_LEN * DM;                   // 384x1024 fp16
    // Partials alias Xh/Wh (dead after proj_gemm): 4096 slots * 4224 B = 16.5 MiB
    float* Part = (float*)Xh;
    float* Out = (float*)d_out;

    convert_kernel<<<1024, 256, 0, stream>>>(X, Wq, Wk, Wv, Xh, Wh);
    proj_gemm_kernel<<<dim3(128, 3), 256, 0, stream>>>(Xh, Wh, Qb, Kb, Vtb);
    flash_partial_kernel<<<576, 256, 0, stream>>>(Qb, Kb, Vtb, Part);
    flash_merge_kernel<<<512, 128, 0, stream>>>(Part, Out);
}